// Round 7
// baseline (227.284 us; speedup 1.0000x reference)
//
#include <hip/hip_runtime.h>

// LocalStructureAnalyse: structure tensor + closed-form 2x2 eigendecomposition.
// x: (16,1,1536,1536) fp32.  Out: 6 planes (16,1536,1536) fp32 concatenated:
//   lambda1(ReLU), lambda2, e11, e12, e21, e22.
//
// R7: 4 output rows per thread, vertically STREAMED: rolling 2-row x window,
// each gradient-product row computed once and accumulated into the (<=3) live
// column-sum sets; a row is eig'd + stored the moment its last tap lands.
// Loads per 16 px: 21 (vs 30 at R6's 2-row). No LDS, no barrier.

typedef float f32x4 __attribute__((ext_vector_type(4)));
typedef float f32x2 __attribute__((ext_vector_type(2)));

constexpr int N_ = 16, H = 1536, W = 1536;

__device__ __forceinline__ void load_row8(const float* __restrict__ p, float d[8]) {
    const f32x2 a = *reinterpret_cast<const f32x2*>(p);
    const f32x4 b = *reinterpret_cast<const f32x4*>(p + 2);
    const f32x2 c = *reinterpret_cast<const f32x2*>(p + 6);
    d[0] = a.x; d[1] = a.y;
    d[2] = b.x; d[3] = b.y; d[4] = b.z; d[5] = b.w;
    d[6] = c.x; d[7] = c.y;
}

__device__ __forceinline__ void eig_row(
    const float S_xx[6], const float S_xy[6], const float S_yy[6],
    float* __restrict__ op, size_t PLANE) {
    f32x4 o_l1, o_l2, o_e11, o_e12, o_e21, o_e22;
    const float inv9 = 1.0f / 9.0f;
#pragma unroll
    for (int k = 0; k < 4; ++k) {
        const float Axx = (S_xx[k] + S_xx[k + 1] + S_xx[k + 2]) * inv9;
        const float Axy = (S_xy[k] + S_xy[k + 1] + S_xy[k + 2]) * inv9;
        const float Ayy = (S_yy[k] + S_yy[k + 1] + S_yy[k + 2]) * inv9;

        const float T  = Axx + Ayy;
        const float Dd = Axx * Ayy - Axy * Axy;
        const float s  = __builtin_amdgcn_sqrtf(fabsf(T * T * 0.25f - Dd));
        const float l1 = T * 0.5f + s;
        const float l2 = T * 0.5f - s;

        float e11 = l1 - Ayy, e12 = Axy;
        float e21 = l2 - Ayy, e22 = Axy;
        const bool small = fabsf(Axy) < 1e-9f;
        e11 = small ? 1.0f : e11;
        e12 = small ? 0.0f : e12;
        e21 = small ? 0.0f : e21;
        e22 = small ? 1.0f : e22;

        const bool lt = fabsf(l1) < fabsf(l2);
        o_l1[k]  = fmaxf(lt ? l1 : l2, 0.0f);   // ReLU only lambda1 (ref typo)
        o_l2[k]  = lt ? l2 : l1;
        o_e11[k] = lt ? e11 : e21;
        o_e12[k] = lt ? e12 : e22;
        o_e21[k] = lt ? e21 : e11;
        o_e22[k] = lt ? e22 : e12;
    }
    __builtin_nontemporal_store(o_l1,  reinterpret_cast<f32x4*>(op));
    __builtin_nontemporal_store(o_l2,  reinterpret_cast<f32x4*>(op + PLANE));
    __builtin_nontemporal_store(o_e11, reinterpret_cast<f32x4*>(op + 2 * PLANE));
    __builtin_nontemporal_store(o_e12, reinterpret_cast<f32x4*>(op + 3 * PLANE));
    __builtin_nontemporal_store(o_e21, reinterpret_cast<f32x4*>(op + 4 * PLANE));
    __builtin_nontemporal_store(o_e22, reinterpret_cast<f32x4*>(op + 5 * PLANE));
}

__global__ __launch_bounds__(256, 4)
void lsa_kernel(const float* __restrict__ x, float* __restrict__ out) {
    const int tid  = threadIdx.x;
    const int wv   = tid >> 6;          // 0..3
    const int lane = tid & 63;          // 0..63
    const int P0   = blockIdx.y * 16 + 4 * wv;     // first of 4 output rows
    const int q0   = blockIdx.x * 256 + 4 * lane;  // first output col (aligned)
    const int n    = blockIdx.z;

    const size_t HW = (size_t)H * W;
    const size_t PLANE = (size_t)N_ * HW;
    const float* __restrict__ xn = x + (size_t)n * HW;
    float* const ob = out + (size_t)n * HW + (size_t)P0 * W + q0;

    const bool interior = (P0 >= 2) & (P0 <= H - 5) & (q0 >= 2) & (q0 <= W - 6);

    if (interior) {
        float Sxx[4][6], Sxy[4][6], Syy[4][6];
        float xrow[2][8];
        const float* rp = xn + (size_t)(P0 - 2) * W + (q0 - 2);
        load_row8(rp, xrow[0]);          // abs row P0-2
        load_row8(rp + W, xrow[1]);      // abs row P0-1

        // product tap rows t=0..5 -> abs rows P0-1 .. P0+4
#pragma unroll
        for (int t = 0; t < 6; ++t) {
            const float* xu_row = xrow[t & 1];        // abs row P0-2+t  (p-1)
            const float* xc_row = xrow[(t + 1) & 1];  // abs row P0-1+t  (p)
            float pxx[6], pxy[6], pyy[6];
#pragma unroll
            for (int m = 0; m < 6; ++m) {
                const float xc = xc_row[m + 1];
                const float xl = xc_row[m];           // x(p, q-1)
                const float xu = xu_row[m + 1];       // x(p-1, q)
                const float gx = xl - xc;
                const float gy = xu - xc;
                pxx[m] = gx * gx; pxy[m] = gx * gy; pyy[m] = gy * gy;
            }
            // prefetch next center row (abs P0+t) into the dead slot
            if (t < 5) load_row8(rp + (size_t)(t + 2) * W, xrow[t & 1]);
            // accumulate into live output rows r: t in [r, r+2]
#pragma unroll
            for (int r = 0; r < 4; ++r) {
                if (t >= r && t <= r + 2) {
                    if (t == r) {
#pragma unroll
                        for (int m = 0; m < 6; ++m) {
                            Sxx[r][m] = pxx[m]; Sxy[r][m] = pxy[m]; Syy[r][m] = pyy[m];
                        }
                    } else {
#pragma unroll
                        for (int m = 0; m < 6; ++m) {
                            Sxx[r][m] += pxx[m]; Sxy[r][m] += pxy[m]; Syy[r][m] += pyy[m];
                        }
                    }
                }
            }
            // emit rows whose last tap just landed (t == r+2)
            if (t >= 2) {
                const int r = t - 2;
                eig_row(Sxx[r], Sxy[r], Syy[r], ob + (size_t)r * W, PLANE);
            }
        }
    } else {
        // guarded scalar path (edge lanes only)
#pragma unroll
        for (int r = 0; r < 4; ++r) {
            float Sxx[6], Sxy[6], Syy[6];
            const int pr = P0 + r;
#pragma unroll
            for (int m = 0; m < 6; ++m) {
                const int q = q0 - 1 + m;
                float sxx = 0.f, sxy = 0.f, syy = 0.f;
                if (q >= 0 && q < W) {
#pragma unroll
                    for (int d = 0; d < 3; ++d) {
                        const int p = pr - 1 + d;
                        if (p >= 0 && p < H) {
                            const float* prow = xn + (size_t)p * W;
                            const float xc = prow[q];
                            const float xl = (q == 0) ? prow[1] : prow[q - 1];
                            const float xu = (p == 0) ? xn[(size_t)W + q] : prow[q - W];
                            const float gx = xl - xc;
                            const float gy = xu - xc;
                            sxx = fmaf(gx, gx, sxx);
                            sxy = fmaf(gx, gy, sxy);
                            syy = fmaf(gy, gy, syy);
                        }
                    }
                }
                Sxx[m] = sxx; Sxy[m] = sxy; Syy[m] = syy;
            }
            eig_row(Sxx, Sxy, Syy, ob + (size_t)r * W, PLANE);
        }
    }
}

extern "C" void kernel_launch(void* const* d_in, const int* in_sizes, int n_in,
                              void* d_out, int out_size, void* d_ws, size_t ws_size,
                              hipStream_t stream) {
    const float* x = (const float*)d_in[0];
    // d_in[1] is the 3x3 weight, fixed to 1/9 by setup -> folded into inv9.
    float* out = (float*)d_out;

    dim3 grid(W / 256, H / 16, N_);   // 6 x 96 x 16
    dim3 block(256);
    lsa_kernel<<<grid, block, 0, stream>>>(x, out);
}

// Round 8
// 171.764 us; speedup vs baseline: 1.3232x; 1.3232x over previous
//
#include <hip/hip_runtime.h>

// LocalStructureAnalyse: structure tensor + closed-form 2x2 eigendecomposition.
// x: (16,1,1536,1536) fp32.  Out: 6 planes (16,1536,1536) fp32 concatenated:
//   lambda1(ReLU), lambda2, e11, e12, e21, e22.
//
// R8 = R6 (best: 171.6 us, 6.16 TB/s = 98% of measured copy ceiling).
// R7's streamed 4-row variant regressed 32%: its rolling window serialized
// the loads (1 in flight vs R6's 15-deep burst). Keep R6's structure:
// 2 output rows per thread from one 5-row register window, all loads issued
// up front, no LDS, no barrier, raw v_sqrt_f32, 6x f32x4 nt stores per row.

typedef float f32x4 __attribute__((ext_vector_type(4)));
typedef float f32x2 __attribute__((ext_vector_type(2)));

constexpr int N_ = 16, H = 1536, W = 1536;

__device__ __forceinline__ void eig_row(
    const float S_xx[6], const float S_xy[6], const float S_yy[6],
    float* __restrict__ op, size_t PLANE) {
    f32x4 o_l1, o_l2, o_e11, o_e12, o_e21, o_e22;
    const float inv9 = 1.0f / 9.0f;
#pragma unroll
    for (int k = 0; k < 4; ++k) {
        const float Axx = (S_xx[k] + S_xx[k + 1] + S_xx[k + 2]) * inv9;
        const float Axy = (S_xy[k] + S_xy[k + 1] + S_xy[k + 2]) * inv9;
        const float Ayy = (S_yy[k] + S_yy[k + 1] + S_yy[k + 2]) * inv9;

        const float T  = Axx + Ayy;
        const float Dd = Axx * Ayy - Axy * Axy;
        const float s  = __builtin_amdgcn_sqrtf(fabsf(T * T * 0.25f - Dd));
        const float l1 = T * 0.5f + s;
        const float l2 = T * 0.5f - s;

        float e11 = l1 - Ayy, e12 = Axy;
        float e21 = l2 - Ayy, e22 = Axy;
        const bool small = fabsf(Axy) < 1e-9f;
        e11 = small ? 1.0f : e11;
        e12 = small ? 0.0f : e12;
        e21 = small ? 0.0f : e21;
        e22 = small ? 1.0f : e22;

        const bool lt = fabsf(l1) < fabsf(l2);
        o_l1[k]  = fmaxf(lt ? l1 : l2, 0.0f);   // ReLU only lambda1 (ref typo)
        o_l2[k]  = lt ? l2 : l1;
        o_e11[k] = lt ? e11 : e21;
        o_e12[k] = lt ? e12 : e22;
        o_e21[k] = lt ? e21 : e11;
        o_e22[k] = lt ? e22 : e12;
    }
    __builtin_nontemporal_store(o_l1,  reinterpret_cast<f32x4*>(op));
    __builtin_nontemporal_store(o_l2,  reinterpret_cast<f32x4*>(op + PLANE));
    __builtin_nontemporal_store(o_e11, reinterpret_cast<f32x4*>(op + 2 * PLANE));
    __builtin_nontemporal_store(o_e12, reinterpret_cast<f32x4*>(op + 3 * PLANE));
    __builtin_nontemporal_store(o_e21, reinterpret_cast<f32x4*>(op + 4 * PLANE));
    __builtin_nontemporal_store(o_e22, reinterpret_cast<f32x4*>(op + 5 * PLANE));
}

__global__ __launch_bounds__(256, 4)
void lsa_kernel(const float* __restrict__ x, float* __restrict__ out) {
    const int tid  = threadIdx.x;
    const int rsub = tid >> 6;          // 0..3
    const int csub = tid & 63;          // 0..63
    const int P0   = blockIdx.y * 8 + 2 * rsub;   // first of 2 output rows
    const int q0   = blockIdx.x * 256 + 4 * csub; // first output col (16B aligned)
    const int n    = blockIdx.z;

    const size_t HW = (size_t)H * W;
    const size_t PLANE = (size_t)N_ * HW;
    const float* __restrict__ xn = x + (size_t)n * HW;

    float S0xx[6], S0xy[6], S0yy[6];    // vertical sums for output row P0
    float S1xx[6], S1xy[6], S1yy[6];    // vertical sums for output row P0+1

    const bool interior = (P0 >= 2) & (P0 <= H - 3) & (q0 >= 2) & (q0 <= W - 6);

    if (interior) {
        // x window rows P0-2..P0+2, cols q0-2..q0+5 (aligned 8/16/8 loads)
        float xv[5][8];
        const float* rp = xn + (size_t)(P0 - 2) * W + (q0 - 2);
#pragma unroll
        for (int d = 0; d < 5; ++d) {
            const f32x2 a = *reinterpret_cast<const f32x2*>(rp);
            const f32x4 b = *reinterpret_cast<const f32x4*>(rp + 2);
            const f32x2 c = *reinterpret_cast<const f32x2*>(rp + 6);
            xv[d][0] = a.x; xv[d][1] = a.y;
            xv[d][2] = b.x; xv[d][3] = b.y; xv[d][4] = b.z; xv[d][5] = b.w;
            xv[d][6] = c.x; xv[d][7] = c.y;
            rp += W;
        }
#pragma unroll
        for (int m = 0; m < 6; ++m) {
            S0xx[m] = 0.f; S0xy[m] = 0.f; S0yy[m] = 0.f;
            S1xx[m] = 0.f; S1xy[m] = 0.f; S1yy[m] = 0.f;
        }
        // product tap rows t=0..3 -> abs rows P0-1..P0+2
#pragma unroll
        for (int t = 0; t < 4; ++t) {
#pragma unroll
            for (int m = 0; m < 6; ++m) {
                const float xc = xv[t + 1][m + 1];
                const float xl = xv[t + 1][m];      // x(p, q-1)
                const float xu = xv[t][m + 1];      // x(p-1, q)
                const float gx = xl - xc;
                const float gy = xu - xc;
                const float pxx = gx * gx;
                const float pxy = gx * gy;
                const float pyy = gy * gy;
                if (t < 3) { S0xx[m] += pxx; S0xy[m] += pxy; S0yy[m] += pyy; }
                if (t > 0) { S1xx[m] += pxx; S1xy[m] += pxy; S1yy[m] += pyy; }
            }
        }
    } else {
        // guarded scalar path (edge lanes only)
#pragma unroll
        for (int r = 0; r < 2; ++r) {
            float* Sxx = r ? S1xx : S0xx;
            float* Sxy = r ? S1xy : S0xy;
            float* Syy = r ? S1yy : S0yy;
            const int pr = P0 + r;
#pragma unroll
            for (int m = 0; m < 6; ++m) {
                const int q = q0 - 1 + m;
                float sxx = 0.f, sxy = 0.f, syy = 0.f;
                if (q >= 0 && q < W) {
#pragma unroll
                    for (int d = 0; d < 3; ++d) {
                        const int p = pr - 1 + d;
                        if (p >= 0 && p < H) {
                            const float* prow = xn + (size_t)p * W;
                            const float xc = prow[q];
                            const float xl = (q == 0) ? prow[1] : prow[q - 1];
                            const float xu = (p == 0) ? xn[(size_t)W + q] : prow[q - W];
                            const float gx = xl - xc;
                            const float gy = xu - xc;
                            sxx = fmaf(gx, gx, sxx);
                            sxy = fmaf(gx, gy, sxy);
                            syy = fmaf(gy, gy, syy);
                        }
                    }
                }
                Sxx[m] = sxx; Sxy[m] = sxy; Syy[m] = syy;
            }
        }
    }

    float* op = out + (size_t)n * HW + (size_t)P0 * W + q0;
    eig_row(S0xx, S0xy, S0yy, op, PLANE);
    eig_row(S1xx, S1xy, S1yy, op + W, PLANE);
}

extern "C" void kernel_launch(void* const* d_in, const int* in_sizes, int n_in,
                              void* d_out, int out_size, void* d_ws, size_t ws_size,
                              hipStream_t stream) {
    const float* x = (const float*)d_in[0];
    // d_in[1] is the 3x3 weight, fixed to 1/9 by setup -> folded into inv9.
    float* out = (float*)d_out;

    dim3 grid(W / 256, H / 8, N_);   // 6 x 192 x 16
    dim3 block(256);
    lsa_kernel<<<grid, block, 0, stream>>>(x, out);
}